// Round 1
// baseline (482.686 us; speedup 1.0000x reference)
//
#include <hip/hip_runtime.h>

// Problem constants (from reference)
#define B_      128
#define NPIX    32      // N = M = 32
#define NNEO    30      // N-2
#define CSTATE  19      // real state channels
#define CPAD    20      // padded channel stride (16B-aligned pixel blocks)
#define OUTD    21      // OUT_DIM
#define ITERS   10
#define THRESHV 0.0007f

#define STATE_ELEMS_PAD (B_ * NPIX * NPIX * CPAD)  // 2,621,440 floats per buffer
#define NCELLS      (B_ * NNEO * NNEO)             // 115,200
#define CLASS_ELEMS (NCELLS * 3)                   // 345,600

// ---------------------------------------------------------------------------
// init: zero ONLY the borders of both (padded) state buffers. Interior pixels
// are fully written by each step before being read (pad channel 19 is written
// as 0 by the step kernels and never used in arithmetic).
// ---------------------------------------------------------------------------
__global__ void nca_init(float* __restrict__ stateA, float* __restrict__ stateB) {
    int idx = blockIdx.x * blockDim.x + threadIdx.x;
    const int total = B_ * 124 * CPAD;
    if (idx >= total) return;
    int c  = idx % CPAD;
    int t2 = idx / CPAD;
    int cellp = t2 % 124;
    int b    = t2 / 124;
    int i, j;
    if (cellp < 32)      { i = 0;  j = cellp; }
    else if (cellp < 64) { i = 31; j = cellp - 32; }
    else { int k = cellp - 64; i = 1 + (k >> 1); j = (k & 1) ? 31 : 0; }
    size_t off = (((size_t)b * NPIX + i) * NPIX + j) * CPAD + c;
    stateA[off] = 0.0f;
    stateB[off] = 0.0f;
}

// ---------------------------------------------------------------------------
// R11 restructure: ONE THREAD PER CELL, ZERO LDS, ZERO BARRIERS.
//  - 450 blocks x 256 threads == 115,200 == NCELLS exactly (100% active).
//  - All three layer accumulators live in registers with compile-time
//    indices only (rule #20: no runtime-indexed arrays -> no scratch).
//  - fv state gather: 5x global_load_dwordx4 per patch, straight from L2/L3
//    (state working set = 2 x 10.5 MB). These ride vmcnt.
//  - Weights: wave-uniform s_load path (lgkmcnt). vmcnt/lgkmcnt DECOUPLE,
//    unlike the previous LDS-staged design where ds_read + s_load shared
//    lgkmcnt and forced full drains.
//  - Accumulation order per output matches the previous kernel exactly
//    (patches (pr,pc), img row, ch rows, then pos rows) for numerics.
// MODE: 0 = first step (state==0, perc=identity), 1 = mid, 2 = last.
// ---------------------------------------------------------------------------
#define L1ROW(x, r) do { const float* __restrict__ wr = wp + (r) * 30; \
    _Pragma("unroll") for (int o = 0; o < 30; o++) acc[o] += (x) * wr[o]; } while (0)

template<int MODE>
__global__ __launch_bounds__(256, 2)
void nca_cell(const float* __restrict__ img,
              const float* __restrict__ W1, const float* __restrict__ b1,
              const float* __restrict__ W2, const float* __restrict__ b2,
              const float* __restrict__ W3, const float* __restrict__ b3,
              const float* __restrict__ state_old, float* __restrict__ state_new,
              int* __restrict__ perc,
              float* __restrict__ guesses_out, float* __restrict__ class_out)
{
    const int cell = blockIdx.x * 256 + threadIdx.x;   // < NCELLS by construction
    const int b  = cell / (NNEO * NNEO);
    const int ij = cell - b * (NNEO * NNEO);
    const int i  = ij / NNEO;
    const int j  = ij - i * NNEO;

    int px, py;
    if (MODE == 0) { px = i; py = j; }
    else           { px = perc[2 * cell]; py = perc[2 * cell + 1]; }

    const float* __restrict__ ib = img + (size_t)b * (NPIX * NPIX);

    // ---------------- layer 1: 182 -> 30, all 30 in registers -------------
    float acc[30];
#pragma unroll
    for (int o = 0; o < 30; o++) acc[o] = b1[o];

    // patch loops kept ROLLED (body ~600 unrolled FMAs fits I-cache; full
    // 9x unroll would be ~45 KB of code)
#pragma clang loop unroll(disable)
    for (int pr = 0; pr < 3; pr++) {
#pragma clang loop unroll(disable)
        for (int pc = 0; pc < 3; pc++) {
            const float iv = ib[(px + pr) * NPIX + (py + pc)];
            const float* __restrict__ wp = W1 + (pr * 3 + pc) * 20 * 30;
            if (MODE != 0) {
                const float4* __restrict__ sp = (const float4*)
                    (state_old + (((size_t)b * NPIX + (i + pr)) * NPIX + (j + pc)) * CPAD);
                const float4 f0 = sp[0], f1 = sp[1], f2 = sp[2], f3 = sp[3], f4 = sp[4];
                L1ROW(iv, 0);
                L1ROW(f0.x, 1);  L1ROW(f0.y, 2);  L1ROW(f0.z, 3);  L1ROW(f0.w, 4);
                L1ROW(f1.x, 5);  L1ROW(f1.y, 6);  L1ROW(f1.z, 7);  L1ROW(f1.w, 8);
                L1ROW(f2.x, 9);  L1ROW(f2.y, 10); L1ROW(f2.z, 11); L1ROW(f2.w, 12);
                L1ROW(f3.x, 13); L1ROW(f3.y, 14); L1ROW(f3.z, 15); L1ROW(f3.w, 16);
                L1ROW(f4.x, 17); L1ROW(f4.y, 18); L1ROW(f4.z, 19);
            } else {
                L1ROW(iv, 0);   // state == 0 at t=0: skip 19 zero rows
            }
        }
    }
    {
        const float posx = (float)(px - 16) * 0.0625f;
        const float posy = (float)(py - 16) * 0.0625f;
        const float* __restrict__ wp = W1;      // macro-compat base
        L1ROW(posx, 180);
        L1ROW(posy, 181);
    }

    float a1[30];
#pragma unroll
    for (int o = 0; o < 30; o++) a1[o] = fmaxf(acc[o], 0.0f);

    // ---------------- layer 2: 30 -> 30 -----------------------------------
    float h2[30];
#pragma unroll
    for (int o = 0; o < 30; o++) h2[o] = b2[o];
#pragma unroll
    for (int k = 0; k < 30; k++) {
        const float x = a1[k];
        const float* __restrict__ wr = W2 + k * 30;
#pragma unroll
        for (int o = 0; o < 30; o++) h2[o] += x * wr[o];
    }
#pragma unroll
    for (int o = 0; o < 30; o++) h2[o] = fmaxf(h2[o], 0.0f);

    // ---------------- layer 3: 30 -> 21 -----------------------------------
    float ov[21];
#pragma unroll
    for (int c = 0; c < 21; c++) ov[c] = b3[c];
#pragma unroll
    for (int k = 0; k < 30; k++) {
        const float x = h2[k];
        const float* __restrict__ wr = W3 + k * 21;
#pragma unroll
        for (int c = 0; c < 21; c++) ov[c] += x * wr[c];
    }

    // ---------------- outputs --------------------------------------------
    const size_t coff = (((size_t)b * NPIX + (i + 1)) * NPIX + (j + 1)) * CPAD;
    if (MODE == 2) {
        float* __restrict__ g = guesses_out + (size_t)cell * OUTD;
#pragma unroll
        for (int c = 0; c < 21; c++) g[c] = ov[c];
        const float4 c4 = *(const float4*)(state_old + coff + 16); // ch16..19
        float* __restrict__ cs = class_out + (size_t)cell * 3;
        cs[0] = c4.x + ov[16];
        cs[1] = c4.y + ov[17];
        cs[2] = c4.z + ov[18];
    } else {
        float4* __restrict__ ns4 = (float4*)(state_new + coff);
        if (MODE == 0) {
            ns4[0] = make_float4(ov[0],  ov[1],  ov[2],  ov[3]);
            ns4[1] = make_float4(ov[4],  ov[5],  ov[6],  ov[7]);
            ns4[2] = make_float4(ov[8],  ov[9],  ov[10], ov[11]);
            ns4[3] = make_float4(ov[12], ov[13], ov[14], ov[15]);
            ns4[4] = make_float4(ov[16], ov[17], ov[18], 0.0f);
        } else {
            const float4* __restrict__ cs4 = (const float4*)(state_old + coff);
            const float4 c0 = cs4[0], c1 = cs4[1], c2 = cs4[2], c3 = cs4[3], c4 = cs4[4];
            ns4[0] = make_float4(c0.x + ov[0],  c0.y + ov[1],  c0.z + ov[2],  c0.w + ov[3]);
            ns4[1] = make_float4(c1.x + ov[4],  c1.y + ov[5],  c1.z + ov[6],  c1.w + ov[7]);
            ns4[2] = make_float4(c2.x + ov[8],  c2.y + ov[9],  c2.z + ov[10], c2.w + ov[11]);
            ns4[3] = make_float4(c3.x + ov[12], c3.y + ov[13], c3.z + ov[14], c3.w + ov[15]);
            ns4[4] = make_float4(c4.x + ov[16], c4.y + ov[17], c4.z + ov[18], 0.0f);
        }
        int dxm = (ov[19] > THRESHV) ? 1 : ((ov[19] < -THRESHV) ? -1 : 0);
        int dym = (ov[20] > THRESHV) ? 1 : ((ov[20] < -THRESHV) ? -1 : 0);
        px += dxm; py += dym;
        px = (px < 0) ? 0 : ((px > NNEO - 1) ? NNEO - 1 : px);
        py = (py < 0) ? 0 : ((py > NNEO - 1) ? NNEO - 1 : py);
        perc[2 * cell + 0] = px;
        perc[2 * cell + 1] = py;
    }
}

extern "C" void kernel_launch(void* const* d_in, const int* in_sizes, int n_in,
                              void* d_out, int out_size, void* d_ws, size_t ws_size,
                              hipStream_t stream) {
    const float* img = (const float*)d_in[0];
    const float* W1  = (const float*)d_in[1];
    const float* b1  = (const float*)d_in[2];
    const float* W2  = (const float*)d_in[3];
    const float* b2  = (const float*)d_in[4];
    const float* W3  = (const float*)d_in[5];
    const float* b3  = (const float*)d_in[6];

    float* out = (float*)d_out;
    float* class_out   = out;                 // 345,600 floats
    float* guesses_out = out + CLASS_ELEMS;   // 2,419,200 floats

    float* stateA = (float*)d_ws;
    float* stateB = stateA + STATE_ELEMS_PAD;
    int*   perc   = (int*)(stateB + STATE_ELEMS_PAD);

    {
        const int total = B_ * 124 * CPAD;
        nca_init<<<(total + 255) / 256, 256, 0, stream>>>(stateA, stateB);
    }

    const int grid = NCELLS / 256;            // 450 blocks, exact cover
    // t = 0: state==0, perc = identity; writes stateB + perc
    nca_cell<0><<<grid, 256, 0, stream>>>(img, W1, b1, W2, b2, W3, b3,
                                          stateA, stateB, perc,
                                          guesses_out, class_out);
    // t = 1..8: ping-pong
    for (int t = 1; t < ITERS - 1; t++) {
        const float* so = (t & 1) ? stateB : stateA;
        float*       sn = (t & 1) ? stateA : stateB;
        nca_cell<1><<<grid, 256, 0, stream>>>(img, W1, b1, W2, b2, W3, b3,
                                              so, sn, perc,
                                              guesses_out, class_out);
    }
    // t = 9 (odd): reads stateB, emits guesses + class only
    nca_cell<2><<<grid, 256, 0, stream>>>(img, W1, b1, W2, b2, W3, b3,
                                          stateB, stateA, perc,
                                          guesses_out, class_out);
}